// Round 1
// baseline (282.127 us; speedup 1.0000x reference)
//
#include <hip/hip_runtime.h>

// QuantumRNNCell: 6-qubit statevector sim (one wave per batch element,
// one complex amplitude per lane) fused with residual + linear epilogue.
//
// Wire w <-> bit (5-w) of the lane/state index (wire 0 = MSB, pennylane
// default.qubit convention, matches reference reshape (2^w, 2, 2^(5-w))).

#define NQ 6

__global__ __launch_bounds__(256) void qrnn_kernel(
    const float* __restrict__ x,     // (B, 6)
    const float* __restrict__ hx,    // (B, H)
    const float* __restrict__ qw,    // (3, 6)
    const float* __restrict__ fc_w,  // (H, 6)
    const float* __restrict__ fc_b,  // (H,)
    float* __restrict__ out,         // (B, H)
    int B, int H)
{
    const int tid  = blockIdx.x * blockDim.x + threadIdx.x;
    const int lane = threadIdx.x & 63;
    const int b    = tid >> 6;          // one wave per batch element
    if (b >= B) return;

    // ---- input-encoding angles: cos/sin of x/2 (each x value reused by
    //      RX on wire i, RY on wire i-1, RZ on wire i-2) ----
    float cx[6], sx[6];
    #pragma unroll
    for (int i = 0; i < 6; ++i) {
        float a = x[(size_t)b * 6 + i] * 0.5f;
        __sincosf(a, &sx[i], &cx[i]);
    }

    // ---- state: |000000> ----
    float re = (lane == 0) ? 1.0f : 0.0f;
    float im = 0.0f;

    // ---- encoding: RX(x[i]), RY(x[i+1]), RZ(x[i+2]) on wire i ----
    #pragma unroll
    for (int i = 0; i < 6; ++i) {
        const int mask = 1 << (5 - i);
        const bool hi = (lane & mask) != 0;   // d = this lane's bit on wire i
        // RX: U = [[c, -i s], [-i s, c]] ; new = c*mine + (-i s)*partner
        {
            float c = cx[i], s = sx[i];
            float pre = __shfl_xor(re, mask);
            float pim = __shfl_xor(im, mask);
            float nre = c * re + s * pim;
            float nim = c * im - s * pre;
            re = nre; im = nim;
        }
        // RY: U = [[c, -s], [s, c]] ; new = c*mine + (d? s : -s)*partner
        {
            int j = (i + 1) % 6;
            float c = cx[j], s = sx[j];
            float pre = __shfl_xor(re, mask);
            float pim = __shfl_xor(im, mask);
            float ss = hi ? s : -s;
            re = c * re + ss * pre;
            im = c * im + ss * pim;
        }
        // RZ: multiply by e^{(d? +i : -i) theta/2} = (c + i*ss), ss = d? s : -s
        {
            int j = (i + 2) % 6;
            float c = cx[j], s = sx[j];
            float ss = hi ? s : -s;
            float nre = c * re - ss * im;
            float nim = c * im + ss * re;
            re = nre; im = nim;
        }
    }

    // ---- compose the fixed CNOT ring (q -> q+1 mod 6) into ONE lane
    //      permutation: A'[s] = A[g0(g1(...g5(s)...))],
    //      gq(s) = s ^ (((s >> (5-q)) & 1) << (5 - ((q+1)%6))) ----
    int src = lane;
    #pragma unroll
    for (int q = 5; q >= 0; --q) {
        int cb = 5 - q;
        int tb = 5 - ((q + 1) % 6);
        src ^= ((src >> cb) & 1) << tb;
    }

    // ---- variational layers: RY(qw[l][q]) on each wire, then CNOT ring ----
    #pragma unroll
    for (int l = 0; l < 3; ++l) {
        #pragma unroll
        for (int q = 0; q < 6; ++q) {
            float th = qw[l * 6 + q] * 0.5f;   // wave-uniform, L2-resident
            float c, s;
            __sincosf(th, &s, &c);
            const int mask = 1 << (5 - q);
            float pre = __shfl_xor(re, mask);
            float pim = __shfl_xor(im, mask);
            float ss = (lane & mask) ? s : -s;
            re = c * re + ss * pre;
            im = c * im + ss * pim;
        }
        re = __shfl(re, src);
        im = __shfl(im, src);
    }

    // ---- PauliZ expvals: q6[j] = sum_s (1 - 2*bit_{5-j}(s)) * |amp_s|^2 ----
    const float p = re * re + im * im;
    float q6[6];
    #pragma unroll
    for (int j = 0; j < 6; ++j) {
        float v = (lane & (1 << (5 - j))) ? -p : p;
        #pragma unroll
        for (int m = 1; m < 64; m <<= 1) v += __shfl_xor(v, m);
        q6[j] = v;   // identical in every lane after full butterfly
    }

    // ---- epilogue: out[b][h] = hx[b][h] + sum_j q6[j]*fc_w[h][j] + fc_b[h]
    //      float4 per lane; fc_w rows h..h+3 are 24 floats = 6 aligned float4
    const float4* hx4 = (const float4*)(hx + (size_t)b * H);
    float4*       ot4 = (float4*)(out + (size_t)b * H);
    const float4* w4  = (const float4*)fc_w;
    const float4* bb4 = (const float4*)fc_b;
    const int nChunks = H >> 8;   // H/256 float4-chunks per wave (H=1024 -> 4)
    for (int k = 0; k < nChunks; ++k) {
        int h4 = k * 64 + lane;                 // float4 index; h = 4*h4
        float4 hv = hx4[h4];
        float4 bv = bb4[h4];
        int wb = h4 * 6;
        float4 a0 = w4[wb + 0], a1 = w4[wb + 1], a2 = w4[wb + 2];
        float4 a3 = w4[wb + 3], a4 = w4[wb + 4], a5 = w4[wb + 5];
        float4 r;
        r.x = hv.x + bv.x + q6[0]*a0.x + q6[1]*a0.y + q6[2]*a0.z + q6[3]*a0.w + q6[4]*a1.x + q6[5]*a1.y;
        r.y = hv.y + bv.y + q6[0]*a1.z + q6[1]*a1.w + q6[2]*a2.x + q6[3]*a2.y + q6[4]*a2.z + q6[5]*a2.w;
        r.z = hv.z + bv.z + q6[0]*a3.x + q6[1]*a3.y + q6[2]*a3.z + q6[3]*a3.w + q6[4]*a4.x + q6[5]*a4.y;
        r.w = hv.w + bv.w + q6[0]*a4.z + q6[1]*a4.w + q6[2]*a5.x + q6[3]*a5.y + q6[4]*a5.z + q6[5]*a5.w;
        ot4[h4] = r;
    }
}

extern "C" void kernel_launch(void* const* d_in, const int* in_sizes, int n_in,
                              void* d_out, int out_size, void* d_ws, size_t ws_size,
                              hipStream_t stream) {
    const float* x    = (const float*)d_in[0];   // (B, 6)
    const float* hx   = (const float*)d_in[1];   // (B, H)
    const float* qw   = (const float*)d_in[2];   // (3, 6)
    const float* fc_w = (const float*)d_in[3];   // (H, 6)
    const float* fc_b = (const float*)d_in[4];   // (H,)
    float* out = (float*)d_out;

    const int B = in_sizes[0] / NQ;              // 32768
    const int H = in_sizes[4];                   // 1024

    // one wave (64 lanes) per batch element; 4 waves per 256-thread block
    const int threads = 256;
    const int blocks  = (B * 64 + threads - 1) / threads;
    qrnn_kernel<<<blocks, threads, 0, stream>>>(x, hx, qw, fc_w, fc_b, out, B, H);
}

// Round 2
// 267.889 us; speedup vs baseline: 1.0531x; 1.0531x over previous
//
#include <hip/hip_runtime.h>

// QuantumRNNCell, v2: shuffle-free sim.
//   Kernel 1 (sim): ONE THREAD per batch element holds all 64 complex
//     amplitudes in registers. Gates are pure VALU (ILP=32 pairs); the fixed
//     CNOT ring is a compile-time register permutation (zero instructions).
//     Writes q6 (B,6) PauliZ expvals to d_ws.
//   Kernel 2 (epilogue): streaming out = hx + q6 @ fc_w^T + fc_b.
//
// Wire w <-> bit (5-w) of the state index (wire 0 = MSB, pennylane order).

#define NQ 6
#define DIM 64

// ---- composed CNOT ring permutation: A'[s] = A[PS.v[s]] ----
struct Perm { int v[DIM]; };
constexpr Perm make_perm() {
    Perm p{};
    for (int s = 0; s < DIM; ++s) {
        int src = s;
        for (int q = 5; q >= 0; --q) {          // apply g5 first, g0 last
            int cb = 5 - q;                      // control bit of CNOT(q, q+1)
            int tb = 5 - ((q + 1) % 6);          // target bit
            src ^= ((src >> cb) & 1) << tb;
        }
        p.v[s] = src;
    }
    return p;
}
constexpr Perm PS = make_perm();

// pair indices for bit BB: p in [0,32) -> (s0, s1 = s0 | 1<<BB)
// RX: [[c,-is],[-is,c]]
template<int BB>
__device__ __forceinline__ void rx_gate(float* sr, float* si, float c, float sn) {
    constexpr int m = 1 << BB;
    #pragma unroll
    for (int p = 0; p < 32; ++p) {
        const int s0 = ((p & ~(m - 1)) << 1) | (p & (m - 1));
        const int s1 = s0 | m;
        float a0r = sr[s0], a0i = si[s0], a1r = sr[s1], a1i = si[s1];
        sr[s0] = c * a0r + sn * a1i;
        si[s0] = c * a0i - sn * a1r;
        sr[s1] = c * a1r + sn * a0i;
        si[s1] = c * a1i - sn * a0r;
    }
}

// RY: [[c,-s],[s,c]]
template<int BB>
__device__ __forceinline__ void ry_gate(float* sr, float* si, float c, float sn) {
    constexpr int m = 1 << BB;
    #pragma unroll
    for (int p = 0; p < 32; ++p) {
        const int s0 = ((p & ~(m - 1)) << 1) | (p & (m - 1));
        const int s1 = s0 | m;
        float a0r = sr[s0], a0i = si[s0], a1r = sr[s1], a1i = si[s1];
        sr[s0] = c * a0r - sn * a1r;
        si[s0] = c * a0i - sn * a1i;
        sr[s1] = sn * a0r + c * a1r;
        si[s1] = sn * a0i + c * a1i;
    }
}

// RZ: diag(e^{-i t/2}, e^{+i t/2})
template<int BB>
__device__ __forceinline__ void rz_gate(float* sr, float* si, float c, float sn) {
    constexpr int m = 1 << BB;
    #pragma unroll
    for (int s = 0; s < DIM; ++s) {
        float r = sr[s], i2 = si[s];
        if (s & m) { sr[s] = c * r - sn * i2;  si[s] = c * i2 + sn * r; }
        else       { sr[s] = c * r + sn * i2;  si[s] = c * i2 - sn * r; }
    }
}

__device__ __forceinline__ void cnot_ring(float* sr, float* si) {
    float tr[DIM], ti[DIM];
    #pragma unroll
    for (int s = 0; s < DIM; ++s) { tr[s] = sr[PS.v[s]]; ti[s] = si[PS.v[s]]; }
    #pragma unroll
    for (int s = 0; s < DIM; ++s) { sr[s] = tr[s]; si[s] = ti[s]; }
}

__global__ __launch_bounds__(64, 1) void qrnn_sim_kernel(
    const float* __restrict__ x,     // (B, 6)
    const float* __restrict__ qw,    // (3, 6)
    float* __restrict__ q6,          // (B, 6) out
    int B)
{
    const int b = blockIdx.x * 64 + threadIdx.x;
    if (b >= B) return;

    float cx[6], sx[6];
    #pragma unroll
    for (int i = 0; i < 6; ++i)
        __sincosf(x[(size_t)b * 6 + i] * 0.5f, &sx[i], &cx[i]);

    float sr[DIM], si[DIM];
    #pragma unroll
    for (int s = 0; s < DIM; ++s) { sr[s] = (s == 0) ? 1.0f : 0.0f; si[s] = 0.0f; }

    // encoding: RX(x[i]), RY(x[i+1]), RZ(x[i+2]) on wire i (bit 5-i)
    #define ENC_WIRE(i) \
        rx_gate<5-(i)>(sr, si, cx[(i)],       sx[(i)]); \
        ry_gate<5-(i)>(sr, si, cx[((i)+1)%6], sx[((i)+1)%6]); \
        rz_gate<5-(i)>(sr, si, cx[((i)+2)%6], sx[((i)+2)%6]);
    ENC_WIRE(0) ENC_WIRE(1) ENC_WIRE(2) ENC_WIRE(3) ENC_WIRE(4) ENC_WIRE(5)
    #undef ENC_WIRE

    // variational layers: RY(qw[l][q]) on wire q, then CNOT ring
    #define VAR_GATE(l, q) { \
        float c, s2; __sincosf(qw[(l)*6+(q)] * 0.5f, &s2, &c); \
        ry_gate<5-(q)>(sr, si, c, s2); }
    #define VAR_LAYER(l) \
        VAR_GATE(l,0) VAR_GATE(l,1) VAR_GATE(l,2) \
        VAR_GATE(l,3) VAR_GATE(l,4) VAR_GATE(l,5) \
        cnot_ring(sr, si);
    VAR_LAYER(0) VAR_LAYER(1) VAR_LAYER(2)
    #undef VAR_LAYER
    #undef VAR_GATE

    // PauliZ expvals: q[j] = sum_s (1 - 2*bit_{5-j}(s)) * |amp_s|^2
    float q[6] = {0.f, 0.f, 0.f, 0.f, 0.f, 0.f};
    #pragma unroll
    for (int s = 0; s < DIM; ++s) {
        float p = sr[s] * sr[s] + si[s] * si[s];
        #pragma unroll
        for (int j = 0; j < 6; ++j)
            q[j] += (s & (1 << (5 - j))) ? -p : p;   // sign is compile-time
    }
    #pragma unroll
    for (int j = 0; j < 6; ++j) q6[(size_t)b * 6 + j] = q[j];
}

// ---- epilogue: out[b][h] = hx[b][h] + sum_j q6[b][j]*fc_w[h][j] + fc_b[h] ----
#define EPI_ROWS 16

__global__ __launch_bounds__(256) void qrnn_epi_kernel(
    const float* __restrict__ hx,    // (B, H)
    const float* __restrict__ q6,    // (B, 6)
    const float* __restrict__ fc_w,  // (H, 6)
    const float* __restrict__ fc_b,  // (H,)
    float* __restrict__ out,         // (B, H)
    int B, int H)
{
    const int H4 = H >> 2;
    const int b0 = blockIdx.x * EPI_ROWS;
    for (int h4 = threadIdx.x; h4 < H4; h4 += blockDim.x) {
        // this thread's 4 fc_w rows (24 floats = 6 aligned float4) + bias
        const float4* w4 = (const float4*)fc_w;
        const int wb = h4 * 6;
        float4 a0 = w4[wb + 0], a1 = w4[wb + 1], a2 = w4[wb + 2];
        float4 a3 = w4[wb + 3], a4 = w4[wb + 4], a5 = w4[wb + 5];
        float4 bv = ((const float4*)fc_b)[h4];
        #pragma unroll
        for (int r = 0; r < EPI_ROWS; ++r) {
            const int b = b0 + r;
            if (b >= B) break;
            const float* qb = q6 + (size_t)b * 6;     // wave-uniform -> s_load
            float q0 = qb[0], q1 = qb[1], q2 = qb[2];
            float q3 = qb[3], q4 = qb[4], q5 = qb[5];
            float4 hv = ((const float4*)(hx + (size_t)b * H))[h4];
            float4 rres;
            rres.x = hv.x + bv.x + q0*a0.x + q1*a0.y + q2*a0.z + q3*a0.w + q4*a1.x + q5*a1.y;
            rres.y = hv.y + bv.y + q0*a1.z + q1*a1.w + q2*a2.x + q3*a2.y + q4*a2.z + q5*a2.w;
            rres.z = hv.z + bv.z + q0*a3.x + q1*a3.y + q2*a3.z + q3*a3.w + q4*a4.x + q5*a4.y;
            rres.w = hv.w + bv.w + q0*a4.z + q1*a4.w + q2*a5.x + q3*a5.y + q4*a5.z + q5*a5.w;
            ((float4*)(out + (size_t)b * H))[h4] = rres;
        }
    }
}

extern "C" void kernel_launch(void* const* d_in, const int* in_sizes, int n_in,
                              void* d_out, int out_size, void* d_ws, size_t ws_size,
                              hipStream_t stream) {
    const float* x    = (const float*)d_in[0];   // (B, 6)
    const float* hx   = (const float*)d_in[1];   // (B, H)
    const float* qw   = (const float*)d_in[2];   // (3, 6)
    const float* fc_w = (const float*)d_in[3];   // (H, 6)
    const float* fc_b = (const float*)d_in[4];   // (H,)
    float* out = (float*)d_out;

    const int B = in_sizes[0] / NQ;              // 32768
    const int H = in_sizes[4];                   // 1024

    float* q6 = (float*)d_ws;                    // (B, 6) scratch, 768 KB

    qrnn_sim_kernel<<<(B + 63) / 64, 64, 0, stream>>>(x, qw, q6, B);
    qrnn_epi_kernel<<<(B + EPI_ROWS - 1) / EPI_ROWS, 256, 0, stream>>>(
        hx, q6, fc_w, fc_b, out, B, H);
}

// Round 3
// 262.563 us; speedup vs baseline: 1.0745x; 1.0203x over previous
//
#include <hip/hip_runtime.h>

// QuantumRNNCell, v3: shuffle-free sim + batched-load streaming epilogue.
//   Kernel 1 (sim): ONE THREAD per batch element holds all 64 complex
//     amplitudes in registers; gates are pure VALU, CNOT ring is a
//     compile-time register permutation. Writes q6 (B,6) to d_ws.
//   Kernel 2 (epilogue): out = hx + q6 @ fc_w^T + fc_b, with q6 rows staged
//     in LDS and hx loads explicitly batched 8-deep to keep ~8 KiB/wave of
//     HBM traffic in flight (v2 had 1 load in flight -> 2.4 TB/s only).
//
// Wire w <-> bit (5-w) of the state index (wire 0 = MSB, pennylane order).

#define NQ 6
#define DIM 64

// ---- composed CNOT ring permutation: A'[s] = A[PS.v[s]] ----
struct Perm { int v[DIM]; };
constexpr Perm make_perm() {
    Perm p{};
    for (int s = 0; s < DIM; ++s) {
        int src = s;
        for (int q = 5; q >= 0; --q) {          // apply g5 first, g0 last
            int cb = 5 - q;                      // control bit of CNOT(q, q+1)
            int tb = 5 - ((q + 1) % 6);          // target bit
            src ^= ((src >> cb) & 1) << tb;
        }
        p.v[s] = src;
    }
    return p;
}
constexpr Perm PS = make_perm();

// RX: [[c,-is],[-is,c]]
template<int BB>
__device__ __forceinline__ void rx_gate(float* sr, float* si, float c, float sn) {
    constexpr int m = 1 << BB;
    #pragma unroll
    for (int p = 0; p < 32; ++p) {
        const int s0 = ((p & ~(m - 1)) << 1) | (p & (m - 1));
        const int s1 = s0 | m;
        float a0r = sr[s0], a0i = si[s0], a1r = sr[s1], a1i = si[s1];
        sr[s0] = c * a0r + sn * a1i;
        si[s0] = c * a0i - sn * a1r;
        sr[s1] = c * a1r + sn * a0i;
        si[s1] = c * a1i - sn * a0r;
    }
}

// RY: [[c,-s],[s,c]]
template<int BB>
__device__ __forceinline__ void ry_gate(float* sr, float* si, float c, float sn) {
    constexpr int m = 1 << BB;
    #pragma unroll
    for (int p = 0; p < 32; ++p) {
        const int s0 = ((p & ~(m - 1)) << 1) | (p & (m - 1));
        const int s1 = s0 | m;
        float a0r = sr[s0], a0i = si[s0], a1r = sr[s1], a1i = si[s1];
        sr[s0] = c * a0r - sn * a1r;
        si[s0] = c * a0i - sn * a1i;
        sr[s1] = sn * a0r + c * a1r;
        si[s1] = sn * a0i + c * a1i;
    }
}

// RZ: diag(e^{-i t/2}, e^{+i t/2})
template<int BB>
__device__ __forceinline__ void rz_gate(float* sr, float* si, float c, float sn) {
    constexpr int m = 1 << BB;
    #pragma unroll
    for (int s = 0; s < DIM; ++s) {
        float r = sr[s], i2 = si[s];
        if (s & m) { sr[s] = c * r - sn * i2;  si[s] = c * i2 + sn * r; }
        else       { sr[s] = c * r + sn * i2;  si[s] = c * i2 - sn * r; }
    }
}

__device__ __forceinline__ void cnot_ring(float* sr, float* si) {
    float tr[DIM], ti[DIM];
    #pragma unroll
    for (int s = 0; s < DIM; ++s) { tr[s] = sr[PS.v[s]]; ti[s] = si[PS.v[s]]; }
    #pragma unroll
    for (int s = 0; s < DIM; ++s) { sr[s] = tr[s]; si[s] = ti[s]; }
}

__global__ __launch_bounds__(64, 1) void qrnn_sim_kernel(
    const float* __restrict__ x,     // (B, 6)
    const float* __restrict__ qw,    // (3, 6)
    float* __restrict__ q6,          // (B, 6) out
    int B)
{
    const int b = blockIdx.x * 64 + threadIdx.x;
    if (b >= B) return;

    float cx[6], sx[6];
    #pragma unroll
    for (int i = 0; i < 6; ++i)
        __sincosf(x[(size_t)b * 6 + i] * 0.5f, &sx[i], &cx[i]);

    float sr[DIM], si[DIM];
    #pragma unroll
    for (int s = 0; s < DIM; ++s) { sr[s] = (s == 0) ? 1.0f : 0.0f; si[s] = 0.0f; }

    // encoding: RX(x[i]), RY(x[i+1]), RZ(x[i+2]) on wire i (bit 5-i)
    #define ENC_WIRE(i) \
        rx_gate<5-(i)>(sr, si, cx[(i)],       sx[(i)]); \
        ry_gate<5-(i)>(sr, si, cx[((i)+1)%6], sx[((i)+1)%6]); \
        rz_gate<5-(i)>(sr, si, cx[((i)+2)%6], sx[((i)+2)%6]);
    ENC_WIRE(0) ENC_WIRE(1) ENC_WIRE(2) ENC_WIRE(3) ENC_WIRE(4) ENC_WIRE(5)
    #undef ENC_WIRE

    // variational layers: RY(qw[l][q]) on wire q, then CNOT ring
    #define VAR_GATE(l, q) { \
        float c, s2; __sincosf(qw[(l)*6+(q)] * 0.5f, &s2, &c); \
        ry_gate<5-(q)>(sr, si, c, s2); }
    #define VAR_LAYER(l) \
        VAR_GATE(l,0) VAR_GATE(l,1) VAR_GATE(l,2) \
        VAR_GATE(l,3) VAR_GATE(l,4) VAR_GATE(l,5) \
        cnot_ring(sr, si);
    VAR_LAYER(0) VAR_LAYER(1) VAR_LAYER(2)
    #undef VAR_LAYER
    #undef VAR_GATE

    // PauliZ expvals: q[j] = sum_s (1 - 2*bit_{5-j}(s)) * |amp_s|^2
    float q[6] = {0.f, 0.f, 0.f, 0.f, 0.f, 0.f};
    #pragma unroll
    for (int s = 0; s < DIM; ++s) {
        float p = sr[s] * sr[s] + si[s] * si[s];
        #pragma unroll
        for (int j = 0; j < 6; ++j)
            q[j] += (s & (1 << (5 - j))) ? -p : p;   // sign is compile-time
    }
    #pragma unroll
    for (int j = 0; j < 6; ++j) q6[(size_t)b * 6 + j] = q[j];
}

// ---- epilogue: out[b][h] = hx[b][h] + sum_j q6[b][j]*fc_w[h][j] + fc_b[h] ----
// Block = 256 threads = one thread per float4 column (H4=256); NB=16 b-rows
// per block, processed as 2 batches of 8 with all 8 hx loads issued before
// any compute/store (8 KiB in flight per wave).
#define NB 16
#define BATCH 8

__global__ __launch_bounds__(256) void qrnn_epi_kernel(
    const float* __restrict__ hx,    // (B, H)
    const float* __restrict__ q6,    // (B, 6)
    const float* __restrict__ fc_w,  // (H, 6)
    const float* __restrict__ fc_b,  // (H,)
    float* __restrict__ out,         // (B, H)
    int H)
{
    const int h4 = threadIdx.x;          // float4 column index, < H/4
    const int b0 = blockIdx.x * NB;

    // stage this block's q6 rows in LDS (NB*6 = 96 floats)
    __shared__ float q6s[NB][6];
    if (threadIdx.x < NB * 6)
        q6s[threadIdx.x / 6][threadIdx.x % 6] = q6[(size_t)b0 * 6 + threadIdx.x];

    // per-thread fc_w rows (24 floats = 6 aligned float4) + bias
    const float4* w4 = (const float4*)fc_w;
    const int wb = h4 * 6;
    float4 a0 = w4[wb + 0], a1 = w4[wb + 1], a2 = w4[wb + 2];
    float4 a3 = w4[wb + 3], a4 = w4[wb + 4], a5 = w4[wb + 5];
    float4 bv = ((const float4*)fc_b)[h4];
    __syncthreads();

    #pragma unroll
    for (int t = 0; t < NB / BATCH; ++t) {
        float4 hv[BATCH];
        // phase 1: issue all BATCH coalesced loads (independent, stay in flight)
        #pragma unroll
        for (int r = 0; r < BATCH; ++r)
            hv[r] = ((const float4*)(hx + (size_t)(b0 + t * BATCH + r) * H))[h4];
        // phase 2: compute + store
        #pragma unroll
        for (int r = 0; r < BATCH; ++r) {
            const float* qb = q6s[t * BATCH + r];
            float q0 = qb[0], q1 = qb[1], q2 = qb[2];
            float q3 = qb[3], q4 = qb[4], q5 = qb[5];
            float4 res;
            res.x = hv[r].x + bv.x + q0*a0.x + q1*a0.y + q2*a0.z + q3*a0.w + q4*a1.x + q5*a1.y;
            res.y = hv[r].y + bv.y + q0*a1.z + q1*a1.w + q2*a2.x + q3*a2.y + q4*a2.z + q5*a2.w;
            res.z = hv[r].z + bv.z + q0*a3.x + q1*a3.y + q2*a3.z + q3*a3.w + q4*a4.x + q5*a4.y;
            res.w = hv[r].w + bv.w + q0*a4.z + q1*a4.w + q2*a5.x + q3*a5.y + q4*a5.z + q5*a5.w;
            ((float4*)(out + (size_t)(b0 + t * BATCH + r) * H))[h4] = res;
        }
    }
}

extern "C" void kernel_launch(void* const* d_in, const int* in_sizes, int n_in,
                              void* d_out, int out_size, void* d_ws, size_t ws_size,
                              hipStream_t stream) {
    const float* x    = (const float*)d_in[0];   // (B, 6)
    const float* hx   = (const float*)d_in[1];   // (B, H)
    const float* qw   = (const float*)d_in[2];   // (3, 6)
    const float* fc_w = (const float*)d_in[3];   // (H, 6)
    const float* fc_b = (const float*)d_in[4];   // (H,)
    float* out = (float*)d_out;

    const int B = in_sizes[0] / NQ;              // 32768
    const int H = in_sizes[4];                   // 1024

    float* q6 = (float*)d_ws;                    // (B, 6) scratch, 768 KB

    qrnn_sim_kernel<<<(B + 63) / 64, 64, 0, stream>>>(x, qw, q6, B);
    // B divisible by NB (32768 / 16 = 2048 blocks); block covers H/4 = 256 cols
    qrnn_epi_kernel<<<B / NB, H / 4, 0, stream>>>(hx, q6, fc_w, fc_b, out, H);
}